// Round 1
// baseline (443.561 us; speedup 1.0000x reference)
//
#include <hip/hip_runtime.h>

#define TSEQ 2048
#define NB 4
#define NH 16
#define HD 64
#define CEMB 1024
#define MROWS (NB*TSEQ)   // 8192

typedef _Float16 half8 __attribute__((ext_vector_type(8)));
typedef float floatx4 __attribute__((ext_vector_type(4)));

__device__ __forceinline__ floatx4 mfma16(half8 a, half8 b, floatx4 c) {
    return __builtin_amdgcn_mfma_f32_16x16x32_f16(a, b, c, 0, 0, 0);
}

// ---------------- fp32 -> fp16 convert (8 elem/thread) ----------------
__global__ __launch_bounds__(256) void cvt_fp32_fp16(const float* __restrict__ in,
                                                     _Float16* __restrict__ out) {
    size_t i = ((size_t)blockIdx.x * 256 + threadIdx.x) * 8;
    float4 a = *(const float4*)(in + i);
    float4 b = *(const float4*)(in + i + 4);
    half8 h;
    h[0] = (_Float16)a.x; h[1] = (_Float16)a.y; h[2] = (_Float16)a.z; h[3] = (_Float16)a.w;
    h[4] = (_Float16)b.x; h[5] = (_Float16)b.y; h[6] = (_Float16)b.z; h[7] = (_Float16)b.w;
    *(half8*)(out + i) = h;
}

// ------------- transpose + convert: in fp32 [R][Ccols] -> out fp16 [Ccols][R] -------------
__global__ __launch_bounds__(256) void transpose_cvt(const float* __restrict__ in,
                                                     _Float16* __restrict__ out,
                                                     int R, int Ccols) {
    __shared__ float tile[32][33];
    int bx = blockIdx.x;  // col tiles
    int by = blockIdx.y;  // row tiles
    int tx = threadIdx.x, ty = threadIdx.y;
    int x = bx * 32 + tx;
#pragma unroll
    for (int i = 0; i < 32; i += 8) {
        int y = by * 32 + ty + i;
        tile[ty + i][tx] = in[(size_t)y * Ccols + x];
    }
    __syncthreads();
#pragma unroll
    for (int i = 0; i < 32; i += 8) {
        int oc = bx * 32 + ty + i;   // original col -> out row
        int orow = by * 32 + tx;     // original row -> out col
        out[(size_t)oc * R + orow] = (_Float16)tile[tx][ty + i];
    }
}

// ---------------- NT GEMM: C[m][n] = sum_k A[m][k] * Bt[n][k] ----------------
// MODE 0: write q/k/v fp16 buffers laid out [which][b][h][t][d] (Ch = base)
// MODE 1: write fp32 row-major [M][N] to Cf
template<int MODE>
__global__ __launch_bounds__(256) void gemm_nt(const _Float16* __restrict__ A,
                                               const _Float16* __restrict__ Bt,
                                               float* __restrict__ Cf,
                                               _Float16* __restrict__ Ch,
                                               int N, int K) {
    __shared__ __align__(16) _Float16 As[128][40];
    __shared__ __align__(16) _Float16 Bs[128][40];

    const int tid = threadIdx.x;
    const int wave = tid >> 6, lane = tid & 63;
    const int wm = wave >> 1, wn = wave & 1;
    const int lrow = lane & 15, lq = lane >> 4;
    const int bm = blockIdx.x, bn = blockIdx.y;

    const int srow = tid >> 1;
    const int skoff = (tid & 1) * 16;
    const _Float16* ag = A + (size_t)(bm * 128 + srow) * K + skoff;
    const _Float16* bg = Bt + (size_t)(bn * 128 + srow) * K + skoff;

    const floatx4 zero = {0.f, 0.f, 0.f, 0.f};
    floatx4 acc[4][4];
#pragma unroll
    for (int i = 0; i < 4; i++)
#pragma unroll
        for (int j = 0; j < 4; j++) acc[i][j] = zero;

    for (int k0 = 0; k0 < K; k0 += 32) {
        int4 a0 = *(const int4*)(ag + k0);
        int4 a1 = *(const int4*)(ag + k0 + 8);
        int4 b0 = *(const int4*)(bg + k0);
        int4 b1 = *(const int4*)(bg + k0 + 8);
        __syncthreads();
        *(int4*)&As[srow][skoff]     = a0;
        *(int4*)&As[srow][skoff + 8] = a1;
        *(int4*)&Bs[srow][skoff]     = b0;
        *(int4*)&Bs[srow][skoff + 8] = b1;
        __syncthreads();
        half8 af[4], bf[4];
#pragma unroll
        for (int i = 0; i < 4; i++) af[i] = *(const half8*)&As[wm * 64 + i * 16 + lrow][lq * 8];
#pragma unroll
        for (int j = 0; j < 4; j++) bf[j] = *(const half8*)&Bs[wn * 64 + j * 16 + lrow][lq * 8];
#pragma unroll
        for (int i = 0; i < 4; i++)
#pragma unroll
            for (int j = 0; j < 4; j++) acc[i][j] = mfma16(af[i], bf[j], acc[i][j]);
    }

    if (MODE == 1) {
#pragma unroll
        for (int i = 0; i < 4; i++) {
            int row = bm * 128 + wm * 64 + i * 16 + lq * 4;
#pragma unroll
            for (int j = 0; j < 4; j++) {
                int col = bn * 128 + wn * 64 + j * 16 + lrow;
#pragma unroll
                for (int r = 0; r < 4; r++)
                    Cf[(size_t)(row + r) * N + col] = acc[i][j][r];
            }
        }
    } else {
#pragma unroll
        for (int j = 0; j < 4; j++) {
            int n = bn * 128 + wn * 64 + j * 16 + lrow;
            int which = n >> 10, c = n & 1023;
            int h = c >> 6, d = c & 63;
            _Float16* dst = Ch + (size_t)which * ((size_t)NB * NH * TSEQ * HD)
                               + (size_t)h * (TSEQ * HD) + d;
#pragma unroll
            for (int i = 0; i < 4; i++) {
                int row = bm * 128 + wm * 64 + i * 16 + lq * 4;
#pragma unroll
                for (int r = 0; r < 4; r++) {
                    int m = row + r;
                    int b = m >> 11, t = m & 2047;
                    dst[(size_t)b * (NH * TSEQ * HD) + (size_t)t * HD] = (_Float16)acc[i][j][r];
                }
            }
        }
    }
}

// ---------------- flash attention: 64-query tile per block, 4 waves ----------------
__global__ __launch_bounds__(256) void attn_fwd(const _Float16* __restrict__ Qg,
                                                const _Float16* __restrict__ Kg,
                                                const _Float16* __restrict__ Vg,
                                                _Float16* __restrict__ Y) {
    __shared__ __align__(16) _Float16 Qs[64][72];
    __shared__ __align__(16) _Float16 Ks[64][72];
    __shared__ __align__(16) _Float16 Vt[64][72];   // Vt[d][key]
    __shared__ __align__(16) _Float16 Ps[64][72];

    const int tid = threadIdx.x;
    const int w = tid >> 6, lane = tid & 63;
    const int lrow = lane & 15, lq = lane >> 4;
    const int qt = blockIdx.x;   // 0..31
    const int bh = blockIdx.y;   // 0..63
    const int b = bh >> 4, h = bh & 15;

    const _Float16* Qb = Qg + (size_t)bh * TSEQ * HD;
    const _Float16* Kb = Kg + (size_t)bh * TSEQ * HD;
    const _Float16* Vb = Vg + (size_t)bh * TSEQ * HD;

    {   // stage Q tile
        int row = tid >> 2, off = (tid & 3) * 16;
        const int4* src = (const int4*)(Qb + (size_t)(qt * 64 + row) * HD + off);
        int4 v0 = src[0], v1 = src[1];
        *(int4*)&Qs[row][off]     = v0;
        *(int4*)&Qs[row][off + 8] = v1;
    }
    __syncthreads();
    half8 qf[2];
    qf[0] = *(const half8*)&Qs[w * 16 + lrow][lq * 8];
    qf[1] = *(const half8*)&Qs[w * 16 + lrow][32 + lq * 8];

    const floatx4 zero = {0.f, 0.f, 0.f, 0.f};
    floatx4 o[4];
#pragma unroll
    for (int j = 0; j < 4; j++) o[j] = zero;
    float mst[4], lst[4];
#pragma unroll
    for (int r = 0; r < 4; r++) { mst[r] = -1e30f; lst[r] = 0.f; }

    const int qrow0 = qt * 64 + w * 16 + lq * 4;

    for (int kt = 0; kt <= qt; ++kt) {
        __syncthreads();   // prior PV reads of Ks/Vt/Ps done
        {   // stage K tile
            int row = tid >> 2, off = (tid & 3) * 16;
            const int4* src = (const int4*)(Kb + (size_t)(kt * 64 + row) * HD + off);
            int4 v0 = src[0], v1 = src[1];
            *(int4*)&Ks[row][off]     = v0;
            *(int4*)&Ks[row][off + 8] = v1;
        }
        {   // stage V transposed: Vt[d][key]
            int key = tid & 63, doff = (tid >> 6) * 16;
            const _Float16* src = Vb + (size_t)(kt * 64 + key) * HD + doff;
            half8 v0 = *(const half8*)src;
            half8 v1 = *(const half8*)(src + 8);
#pragma unroll
            for (int j = 0; j < 8; j++) Vt[doff + j][key] = v0[j];
#pragma unroll
            for (int j = 0; j < 8; j++) Vt[doff + 8 + j][key] = v1[j];
        }
        __syncthreads();

        // S = Q K^T  (per wave: 16 q rows x 64 keys)
        floatx4 s[4];
#pragma unroll
        for (int nj = 0; nj < 4; nj++) {
            half8 kf0 = *(const half8*)&Ks[nj * 16 + lrow][lq * 8];
            half8 kf1 = *(const half8*)&Ks[nj * 16 + lrow][32 + lq * 8];
            floatx4 acc = zero;
            acc = mfma16(qf[0], kf0, acc);
            acc = mfma16(qf[1], kf1, acc);
            s[nj] = acc;
        }

        const bool diag = (kt == qt);
#pragma unroll
        for (int r = 0; r < 4; r++) {
            int qrow = qrow0 + r;
            float mx = -1e30f;
            float sv[4];
#pragma unroll
            for (int nj = 0; nj < 4; nj++) {
                float v = s[nj][r] * 0.125f;
                if (diag) {
                    int kc = kt * 64 + nj * 16 + lrow;
                    if (kc > qrow) v = -1e30f;
                }
                sv[nj] = v;
                mx = fmaxf(mx, v);
            }
#pragma unroll
            for (int off = 1; off < 16; off <<= 1) mx = fmaxf(mx, __shfl_xor(mx, off));
            float mnew = fmaxf(mst[r], mx);
            float alpha = __expf(mst[r] - mnew);
            mst[r] = mnew;
            float rsum = 0.f;
#pragma unroll
            for (int nj = 0; nj < 4; nj++) {
                float p = __expf(sv[nj] - mnew);
                rsum += p;
                Ps[w * 16 + lq * 4 + r][nj * 16 + lrow] = (_Float16)p;
            }
#pragma unroll
            for (int off = 1; off < 16; off <<= 1) rsum += __shfl_xor(rsum, off);
            lst[r] = lst[r] * alpha + rsum;
#pragma unroll
            for (int nj = 0; nj < 4; nj++) o[nj][r] *= alpha;
        }
        __syncthreads();   // Ps visible

        // O += P V   (P: A-operand from LDS; V^T: B-operand from Vt)
#pragma unroll
        for (int ks = 0; ks < 2; ks++) {
            half8 pf = *(const half8*)&Ps[w * 16 + lrow][ks * 32 + lq * 8];
#pragma unroll
            for (int nj = 0; nj < 4; nj++) {
                half8 vf = *(const half8*)&Vt[nj * 16 + lrow][ks * 32 + lq * 8];
                o[nj] = mfma16(pf, vf, o[nj]);
            }
        }
    }

    // epilogue: y[b, t, h*64+d] fp16
#pragma unroll
    for (int nj = 0; nj < 4; nj++) {
#pragma unroll
        for (int r = 0; r < 4; r++) {
            int q = qt * 64 + w * 16 + lq * 4 + r;
            int d = nj * 16 + lrow;
            float val = o[nj][r] / lst[r];
            Y[((size_t)(b * TSEQ + q)) * CEMB + h * HD + d] = (_Float16)val;
        }
    }
}

extern "C" void kernel_launch(void* const* d_in, const int* in_sizes, int n_in,
                              void* d_out, int out_size, void* d_ws, size_t ws_size,
                              hipStream_t stream) {
    const float* x0     = (const float*)d_in[0];
    const float* w_attn = (const float*)d_in[1];
    const float* w_proj = (const float*)d_in[2];
    float* out = (float*)d_out;

    _Float16* xh  = (_Float16*)d_ws;                       // [8192][1024]
    _Float16* wqt = xh  + (size_t)MROWS * CEMB;            // [3072][1024] (w_attn^T)
    _Float16* wpt = wqt + (size_t)3 * CEMB * CEMB;         // [1024][1024] (w_proj^T)
    _Float16* qh  = wpt + (size_t)CEMB * CEMB;             // q/k/v each [64][2048][64]
    _Float16* kh  = qh  + (size_t)MROWS * CEMB;
    _Float16* vh  = kh  + (size_t)MROWS * CEMB;
    _Float16* yh  = vh  + (size_t)MROWS * CEMB;            // [8192][1024]

    cvt_fp32_fp16<<<(MROWS * CEMB) / (256 * 8), 256, 0, stream>>>(x0, xh);
    transpose_cvt<<<dim3(3 * CEMB / 32, CEMB / 32), dim3(32, 8), 0, stream>>>(w_attn, wqt, CEMB, 3 * CEMB);
    transpose_cvt<<<dim3(CEMB / 32, CEMB / 32), dim3(32, 8), 0, stream>>>(w_proj, wpt, CEMB, CEMB);

    gemm_nt<0><<<dim3(MROWS / 128, 3 * CEMB / 128), 256, 0, stream>>>(xh, wqt, nullptr, qh, 3 * CEMB, CEMB);
    attn_fwd<<<dim3(TSEQ / 64, NB * NH), 256, 0, stream>>>(qh, kh, vh, yh);
    gemm_nt<1><<<dim3(MROWS / 128, CEMB / 128), 256, 0, stream>>>(yh, wpt, out, nullptr, CEMB, CEMB);
}

// Round 2
// 352.938 us; speedup vs baseline: 1.2568x; 1.2568x over previous
//
#include <hip/hip_runtime.h>

#define TSEQ 2048
#define NB 4
#define NH 16
#define HD 64
#define CEMB 1024
#define MROWS (NB*TSEQ)   // 8192

typedef _Float16 half8 __attribute__((ext_vector_type(8)));
typedef _Float16 half4_t __attribute__((ext_vector_type(4)));
typedef float floatx4 __attribute__((ext_vector_type(4)));

__device__ __forceinline__ floatx4 mfma16x32(half8 a, half8 b, floatx4 c) {
    return __builtin_amdgcn_mfma_f32_16x16x32_f16(a, b, c, 0, 0, 0);
}
__device__ __forceinline__ floatx4 mfma16x16(half4_t a, half4_t b, floatx4 c) {
    return __builtin_amdgcn_mfma_f32_16x16x16f16(a, b, c, 0, 0, 0);
}

// ---------------- fp32 -> fp16 convert (8 elem/thread) ----------------
__global__ __launch_bounds__(256) void cvt_fp32_fp16(const float* __restrict__ in,
                                                     _Float16* __restrict__ out) {
    size_t i = ((size_t)blockIdx.x * 256 + threadIdx.x) * 8;
    float4 a = *(const float4*)(in + i);
    float4 b = *(const float4*)(in + i + 4);
    half8 h;
    h[0] = (_Float16)a.x; h[1] = (_Float16)a.y; h[2] = (_Float16)a.z; h[3] = (_Float16)a.w;
    h[4] = (_Float16)b.x; h[5] = (_Float16)b.y; h[6] = (_Float16)b.z; h[7] = (_Float16)b.w;
    *(half8*)(out + i) = h;
}

// ------------- transpose + convert: in fp32 [R][Ccols] -> out fp16 [Ccols][R] -------------
__global__ __launch_bounds__(256) void transpose_cvt(const float* __restrict__ in,
                                                     _Float16* __restrict__ out,
                                                     int R, int Ccols) {
    __shared__ float tile[32][33];
    int bx = blockIdx.x;
    int by = blockIdx.y;
    int tx = threadIdx.x, ty = threadIdx.y;
    int x = bx * 32 + tx;
#pragma unroll
    for (int i = 0; i < 32; i += 8) {
        int y = by * 32 + ty + i;
        tile[ty + i][tx] = in[(size_t)y * Ccols + x];
    }
    __syncthreads();
#pragma unroll
    for (int i = 0; i < 32; i += 8) {
        int oc = bx * 32 + ty + i;
        int orow = by * 32 + tx;
        out[(size_t)oc * R + orow] = (_Float16)tile[tx][ty + i];
    }
}

// ---------------- NT GEMM: C[m][n] = sum_k A[m][k] * Bt[n][k] ----------------
template<int MODE>
__global__ __launch_bounds__(256) void gemm_nt(const _Float16* __restrict__ A,
                                               const _Float16* __restrict__ Bt,
                                               float* __restrict__ Cf,
                                               _Float16* __restrict__ Ch,
                                               int N, int K) {
    __shared__ __align__(16) _Float16 As[128][40];
    __shared__ __align__(16) _Float16 Bs[128][40];

    const int tid = threadIdx.x;
    const int wave = tid >> 6, lane = tid & 63;
    const int wm = wave >> 1, wn = wave & 1;
    const int lrow = lane & 15, lq = lane >> 4;
    const int bm = blockIdx.x, bn = blockIdx.y;

    const int srow = tid >> 1;
    const int skoff = (tid & 1) * 16;
    const _Float16* ag = A + (size_t)(bm * 128 + srow) * K + skoff;
    const _Float16* bg = Bt + (size_t)(bn * 128 + srow) * K + skoff;

    const floatx4 zero = {0.f, 0.f, 0.f, 0.f};
    floatx4 acc[4][4];
#pragma unroll
    for (int i = 0; i < 4; i++)
#pragma unroll
        for (int j = 0; j < 4; j++) acc[i][j] = zero;

    for (int k0 = 0; k0 < K; k0 += 32) {
        int4 a0 = *(const int4*)(ag + k0);
        int4 a1 = *(const int4*)(ag + k0 + 8);
        int4 b0 = *(const int4*)(bg + k0);
        int4 b1 = *(const int4*)(bg + k0 + 8);
        __syncthreads();
        *(int4*)&As[srow][skoff]     = a0;
        *(int4*)&As[srow][skoff + 8] = a1;
        *(int4*)&Bs[srow][skoff]     = b0;
        *(int4*)&Bs[srow][skoff + 8] = b1;
        __syncthreads();
        half8 af[4], bf[4];
#pragma unroll
        for (int i = 0; i < 4; i++) af[i] = *(const half8*)&As[wm * 64 + i * 16 + lrow][lq * 8];
#pragma unroll
        for (int j = 0; j < 4; j++) bf[j] = *(const half8*)&Bs[wn * 64 + j * 16 + lrow][lq * 8];
#pragma unroll
        for (int i = 0; i < 4; i++)
#pragma unroll
            for (int j = 0; j < 4; j++) acc[i][j] = mfma16x32(af[i], bf[j], acc[i][j]);
    }

    if (MODE == 1) {
#pragma unroll
        for (int i = 0; i < 4; i++) {
            int row = bm * 128 + wm * 64 + i * 16 + lq * 4;
#pragma unroll
            for (int j = 0; j < 4; j++) {
                int col = bn * 128 + wn * 64 + j * 16 + lrow;
#pragma unroll
                for (int r = 0; r < 4; r++)
                    Cf[(size_t)(row + r) * N + col] = acc[i][j][r];
            }
        }
    } else {
#pragma unroll
        for (int j = 0; j < 4; j++) {
            int n = bn * 128 + wn * 64 + j * 16 + lrow;
            int which = n >> 10, c = n & 1023;
            int h = c >> 6, d = c & 63;
            _Float16* dst = Ch + (size_t)which * ((size_t)NB * NH * TSEQ * HD)
                               + (size_t)h * (TSEQ * HD) + d;
#pragma unroll
            for (int i = 0; i < 4; i++) {
                int row = bm * 128 + wm * 64 + i * 16 + lq * 4;
#pragma unroll
                for (int r = 0; r < 4; r++) {
                    int m = row + r;
                    int b = m >> 11, t = m & 2047;
                    dst[(size_t)b * (NH * TSEQ * HD) + (size_t)t * HD] = (_Float16)acc[i][j][r];
                }
            }
        }
    }
}

// ---------------- flash attention, S^T formulation ----------------
// Block: 64 queries, 4 waves; wave owns 16 queries.
// S^T = K*Q^T via mfma_16x16x32 -> lane holds P^T in exactly the A-operand
// layout of mfma_16x16x16 for P*V: no LDS round-trip for P.
// K/V double-buffered in LDS, ONE barrier per key-tile.
__global__ __launch_bounds__(256, 4) void attn_fwd(const _Float16* __restrict__ Qg,
                                                   const _Float16* __restrict__ Kg,
                                                   const _Float16* __restrict__ Vg,
                                                   _Float16* __restrict__ Y) {
    __shared__ __align__(16) _Float16 Ks[2][64][72];
    __shared__ __align__(16) _Float16 Vt[2][64][72];   // Vt[d][key]

    const int tid = threadIdx.x;
    const int w = tid >> 6, lane = tid & 63;
    const int l16 = lane & 15, quad = lane >> 4;
    const int qt = (int)gridDim.x - 1 - (int)blockIdx.x;  // heavy blocks first
    const int bh = blockIdx.y;
    const int b = bh >> 4, h = bh & 15;

    const _Float16* Qb = Qg + (size_t)bh * TSEQ * HD;
    const _Float16* Kb = Kg + (size_t)bh * TSEQ * HD;
    const _Float16* Vb = Vg + (size_t)bh * TSEQ * HD;

    // Q fragments straight from global (B-operand of 16x16x32):
    // lane needs Q[q = w*16+l16][d = dhalf*32 + quad*8 .. +7]
    const _Float16* qrow = Qb + (size_t)(qt * 64 + w * 16 + l16) * HD;
    const half8 qf0 = *(const half8*)(qrow + quad * 8);
    const half8 qf1 = *(const half8*)(qrow + 32 + quad * 8);

    const floatx4 zero = {0.f, 0.f, 0.f, 0.f};
    floatx4 o[4];
#pragma unroll
    for (int dt = 0; dt < 4; dt++) o[dt] = zero;
    float m_run = -1e30f, l_run = 0.f;

    // staging roles
    const int krow = tid >> 2, koff = (tid & 3) * 16;
    const int vkey = tid & 63, vseg = tid >> 6;

    int4 kreg0, kreg1;
    half8 vreg0, vreg1;
    {   // preload kt = 0
        const _Float16* ksrc = Kb + (size_t)krow * HD + koff;
        kreg0 = *(const int4*)ksrc; kreg1 = *(const int4*)(ksrc + 8);
        const _Float16* vsrc = Vb + (size_t)vkey * HD + vseg * 16;
        vreg0 = *(const half8*)vsrc; vreg1 = *(const half8*)(vsrc + 8);
    }
    {   // write buf 0
        *(int4*)&Ks[0][krow][koff]     = kreg0;
        *(int4*)&Ks[0][krow][koff + 8] = kreg1;
#pragma unroll
        for (int j = 0; j < 8; j++) Vt[0][vseg * 16 + j][vkey] = vreg0[j];
#pragma unroll
        for (int j = 0; j < 8; j++) Vt[0][vseg * 16 + 8 + j][vkey] = vreg1[j];
    }

    const float kscale = 0.125f * 1.44269504f;   // 1/sqrt(64) in log2 domain
    const int qmine = w * 16 + l16;              // this lane's softmax query (in-tile)
    const int shbase = quad * 4;                 // O-row / key sub-base

    int buf = 0;
    for (int kt = 0; kt <= qt; ++kt) {
        __syncthreads();   // buf fully staged; all waves done with buf^1
        const bool haveNext = (kt < qt);
        if (haveNext) {    // issue next tile's global loads early
            const _Float16* ksrc = Kb + (size_t)((kt + 1) * 64 + krow) * HD + koff;
            kreg0 = *(const int4*)ksrc; kreg1 = *(const int4*)(ksrc + 8);
            const _Float16* vsrc = Vb + (size_t)((kt + 1) * 64 + vkey) * HD + vseg * 16;
            vreg0 = *(const half8*)vsrc; vreg1 = *(const half8*)(vsrc + 8);
        }

        const int klim = (kt == qt) ? qmine : 1024;   // mask keys > klim (in-tile)
        float sv[4][4];
#pragma unroll
        for (int nj = 0; nj < 4; nj++) {
            half8 kf0 = *(const half8*)&Ks[buf][nj * 16 + l16][quad * 8];
            half8 kf1 = *(const half8*)&Ks[buf][nj * 16 + l16][32 + quad * 8];
            floatx4 st = mfma16x32(kf0, qf0, zero);
            st = mfma16x32(kf1, qf1, st);
            // st[r] = S^T[key = nj*16 + quad*4 + r][q = w*16+l16]
#pragma unroll
            for (int r = 0; r < 4; r++) {
                float v = st[r] * kscale;
                int key = nj * 16 + shbase + r;
                sv[nj][r] = (key > klim) ? -1e30f : v;
            }
        }

        float mx = -1e30f;
#pragma unroll
        for (int nj = 0; nj < 4; nj++)
#pragma unroll
            for (int r = 0; r < 4; r++) mx = fmaxf(mx, sv[nj][r]);
        mx = fmaxf(mx, __shfl_xor(mx, 16));
        mx = fmaxf(mx, __shfl_xor(mx, 32));
        float mnew = fmaxf(m_run, mx);
        float alphaq = __builtin_amdgcn_exp2f(m_run - mnew);
        m_run = mnew;

        half4_t pf[4];
        float rsum = 0.f;
#pragma unroll
        for (int nj = 0; nj < 4; nj++)
#pragma unroll
            for (int r = 0; r < 4; r++) {
                float p = __builtin_amdgcn_exp2f(sv[nj][r] - mnew);
                rsum += p;
                pf[nj][r] = (_Float16)p;
            }
        rsum += __shfl_xor(rsum, 16);
        rsum += __shfl_xor(rsum, 32);
        l_run = l_run * alphaq + rsum;

        // O rows are queries quad*4+r -> fetch their alpha via shuffle
        float ao[4];
#pragma unroll
        for (int r = 0; r < 4; r++) ao[r] = __shfl(alphaq, shbase + r);
#pragma unroll
        for (int dt = 0; dt < 4; dt++)
#pragma unroll
            for (int r = 0; r < 4; r++) o[dt][r] *= ao[r];

        // O += P*V : A = pf (in registers), B = V^T fragment from LDS
#pragma unroll
        for (int nj = 0; nj < 4; nj++)
#pragma unroll
            for (int dt = 0; dt < 4; dt++) {
                half4_t vf = *(const half4_t*)&Vt[buf][dt * 16 + l16][nj * 16 + shbase];
                o[dt] = mfma16x16(pf[nj], vf, o[dt]);
            }

        if (haveNext) {   // write next buffer (vmcnt waited here, after compute)
            int nb = buf ^ 1;
            *(int4*)&Ks[nb][krow][koff]     = kreg0;
            *(int4*)&Ks[nb][krow][koff + 8] = kreg1;
#pragma unroll
            for (int j = 0; j < 8; j++) Vt[nb][vseg * 16 + j][vkey] = vreg0[j];
#pragma unroll
            for (int j = 0; j < 8; j++) Vt[nb][vseg * 16 + 8 + j][vkey] = vreg1[j];
            buf = nb;
        }
    }

    float linv[4];
#pragma unroll
    for (int r = 0; r < 4; r++) linv[r] = 1.0f / __shfl(l_run, shbase + r);
#pragma unroll
    for (int dt = 0; dt < 4; dt++)
#pragma unroll
        for (int r = 0; r < 4; r++) {
            int q = qt * 64 + w * 16 + quad * 4 + r;
            int d = dt * 16 + l16;
            Y[((size_t)(b * TSEQ + q)) * CEMB + h * HD + d] = (_Float16)(o[dt][r] * linv[r]);
        }
}

extern "C" void kernel_launch(void* const* d_in, const int* in_sizes, int n_in,
                              void* d_out, int out_size, void* d_ws, size_t ws_size,
                              hipStream_t stream) {
    const float* x0     = (const float*)d_in[0];
    const float* w_attn = (const float*)d_in[1];
    const float* w_proj = (const float*)d_in[2];
    float* out = (float*)d_out;

    _Float16* xh  = (_Float16*)d_ws;                       // [8192][1024]
    _Float16* wqt = xh  + (size_t)MROWS * CEMB;            // [3072][1024] (w_attn^T)
    _Float16* wpt = wqt + (size_t)3 * CEMB * CEMB;         // [1024][1024] (w_proj^T)
    _Float16* qh  = wpt + (size_t)CEMB * CEMB;             // q/k/v each [64][2048][64]
    _Float16* kh  = qh  + (size_t)MROWS * CEMB;
    _Float16* vh  = kh  + (size_t)MROWS * CEMB;
    _Float16* yh  = vh  + (size_t)MROWS * CEMB;            // [8192][1024]

    cvt_fp32_fp16<<<(MROWS * CEMB) / (256 * 8), 256, 0, stream>>>(x0, xh);
    transpose_cvt<<<dim3(3 * CEMB / 32, CEMB / 32), dim3(32, 8), 0, stream>>>(w_attn, wqt, CEMB, 3 * CEMB);
    transpose_cvt<<<dim3(CEMB / 32, CEMB / 32), dim3(32, 8), 0, stream>>>(w_proj, wpt, CEMB, CEMB);

    gemm_nt<0><<<dim3(MROWS / 128, 3 * CEMB / 128), 256, 0, stream>>>(xh, wqt, nullptr, qh, 3 * CEMB, CEMB);
    attn_fwd<<<dim3(TSEQ / 64, NB * NH), 256, 0, stream>>>(qh, kh, vh, yh);
    gemm_nt<1><<<dim3(MROWS / 128, CEMB / 128), 256, 0, stream>>>(yh, wpt, out, nullptr, CEMB, CEMB);
}

// Round 3
// 273.777 us; speedup vs baseline: 1.6202x; 1.2891x over previous
//
#include <hip/hip_runtime.h>

#define TSEQ 2048
#define NB 4
#define NH 16
#define HD 64
#define CEMB 1024
#define MROWS (NB*TSEQ)   // 8192

typedef _Float16 half8 __attribute__((ext_vector_type(8)));
typedef _Float16 half4_t __attribute__((ext_vector_type(4)));
typedef float floatx4 __attribute__((ext_vector_type(4)));

__device__ __forceinline__ floatx4 mfma16x32(half8 a, half8 b, floatx4 c) {
    return __builtin_amdgcn_mfma_f32_16x16x32_f16(a, b, c, 0, 0, 0);
}

__device__ __forceinline__ void async16(const _Float16* g, _Float16* l) {
    __builtin_amdgcn_global_load_lds((const __attribute__((address_space(1))) void*)g,
                                     (__attribute__((address_space(3))) void*)l, 16, 0, 0);
}

// ---------------- fp32 -> fp16 convert (8 elem/thread) ----------------
__global__ __launch_bounds__(256) void cvt_fp32_fp16(const float* __restrict__ in,
                                                     _Float16* __restrict__ out) {
    size_t i = ((size_t)blockIdx.x * 256 + threadIdx.x) * 8;
    float4 a = *(const float4*)(in + i);
    float4 b = *(const float4*)(in + i + 4);
    half8 h;
    h[0] = (_Float16)a.x; h[1] = (_Float16)a.y; h[2] = (_Float16)a.z; h[3] = (_Float16)a.w;
    h[4] = (_Float16)b.x; h[5] = (_Float16)b.y; h[6] = (_Float16)b.z; h[7] = (_Float16)b.w;
    *(half8*)(out + i) = h;
}

// ------------- transpose + convert: in fp32 [R][Ccols] -> out fp16 [Ccols][R] -------------
__global__ __launch_bounds__(256) void transpose_cvt(const float* __restrict__ in,
                                                     _Float16* __restrict__ out,
                                                     int R, int Ccols) {
    __shared__ float tile[32][33];
    int bx = blockIdx.x;
    int by = blockIdx.y;
    int tx = threadIdx.x, ty = threadIdx.y;
    int x = bx * 32 + tx;
#pragma unroll
    for (int i = 0; i < 32; i += 8) {
        int y = by * 32 + ty + i;
        tile[ty + i][tx] = in[(size_t)y * Ccols + x];
    }
    __syncthreads();
#pragma unroll
    for (int i = 0; i < 32; i += 8) {
        int oc = bx * 32 + ty + i;
        int orow = by * 32 + tx;
        out[(size_t)oc * R + orow] = (_Float16)tile[tx][ty + i];
    }
}

// ---------------- NT GEMM: C[m][n] = sum_k A[m][k] * Bt[n][k] ----------------
// m97-style: global_load_lds width-16 staging, BK=32, unpadded LDS + XOR-4
// source swizzle, double-buffered 1-barrier K-loop.
// MODE 0: write Q/K fp16 [which][b][h][t][d] to Ch, V transposed [bh][d][t] to VTh.
// MODE 1: write fp32 row-major [M][N] to Cf.
template<int MODE>
__global__ __launch_bounds__(256, 4) void gemm_nt(const _Float16* __restrict__ A,
                                                  const _Float16* __restrict__ Bt,
                                                  float* __restrict__ Cf,
                                                  _Float16* __restrict__ Ch,
                                                  _Float16* __restrict__ VTh,
                                                  int N, int K) {
    __shared__ __align__(16) _Float16 As[2][4096];   // [128][32] halves, XOR-4 swizzled
    __shared__ __align__(16) _Float16 Bs[2][4096];

    const int tid = threadIdx.x;
    const int wave = tid >> 6, lane = tid & 63;
    const int wm = wave >> 1, wn = wave & 1;
    const int l16 = lane & 15, lq = lane >> 4;
    const int bm = blockIdx.x, bn = blockIdx.y;

    const int srow = lane >> 2;                                // within-chunk row
    const int scol = ((lane & 3) ^ ((lane >> 2) & 3)) * 8;     // swizzled col (halves)
    const _Float16* Abase = A + (size_t)(bm * 128) * K;
    const _Float16* Bbase = Bt + (size_t)(bn * 128) * K;

    const floatx4 zero = {0.f, 0.f, 0.f, 0.f};
    floatx4 acc[4][4];
#pragma unroll
    for (int i = 0; i < 4; i++)
#pragma unroll
        for (int j = 0; j < 4; j++) acc[i][j] = zero;

    auto stage = [&](int bf, int k0) {
#pragma unroll
        for (int cc = 0; cc < 2; cc++) {
            const int c = wave * 2 + cc;
            const size_t gofs = (size_t)(c * 16 + srow) * K + k0 + scol;
            async16(Abase + gofs, &As[bf][c * 512]);
            async16(Bbase + gofs, &Bs[bf][c * 512]);
        }
    };

    stage(0, 0);
    int buf = 0;
    for (int k0 = 0; k0 < K; k0 += 32) {
        __syncthreads();                 // implicit vmcnt(0): buf staged, buf^1 free
        if (k0 + 32 < K) stage(buf ^ 1, k0 + 32);
        half8 af[4], bf[4];
#pragma unroll
        for (int i = 0; i < 4; i++) {
            const int sw = (lq ^ (l16 & 3)) * 8;
            af[i] = *(const half8*)&As[buf][(wm * 64 + i * 16 + l16) * 32 + sw];
            bf[i] = *(const half8*)&Bs[buf][(wn * 64 + i * 16 + l16) * 32 + sw];
        }
#pragma unroll
        for (int i = 0; i < 4; i++)
#pragma unroll
            for (int j = 0; j < 4; j++)
                acc[i][j] = mfma16x32(af[i], bf[j], acc[i][j]);
        buf ^= 1;
    }

    if (MODE == 1) {
#pragma unroll
        for (int i = 0; i < 4; i++) {
            int row = bm * 128 + wm * 64 + i * 16 + lq * 4;
#pragma unroll
            for (int j = 0; j < 4; j++) {
                int col = bn * 128 + wn * 64 + j * 16 + l16;
#pragma unroll
                for (int r = 0; r < 4; r++)
                    Cf[(size_t)(row + r) * N + col] = acc[i][j][r];
            }
        }
    } else {
        const int which = bn >> 3;   // block-uniform (128 | 1024)
        if (which < 2) {
#pragma unroll
            for (int j = 0; j < 4; j++) {
                int n = bn * 128 + wn * 64 + j * 16 + l16;
                int c = n & 1023, h = c >> 6, d = c & 63;
                _Float16* dst = Ch + (size_t)which * ((size_t)MROWS * CEMB)
                                   + (size_t)h * (TSEQ * HD) + d;
#pragma unroll
                for (int i = 0; i < 4; i++) {
                    int row = bm * 128 + wm * 64 + i * 16 + lq * 4;
#pragma unroll
                    for (int r = 0; r < 4; r++) {
                        int m = row + r;
                        int b = m >> 11, t = m & 2047;
                        dst[(size_t)b * (NH * TSEQ * HD) + (size_t)t * HD] = (_Float16)acc[i][j][r];
                    }
                }
            }
        } else {
            // V^T: [bh][d][t], 4 consecutive t -> packed b64 store
#pragma unroll
            for (int j = 0; j < 4; j++) {
                int n = bn * 128 + wn * 64 + j * 16 + l16;
                int c = n & 1023, h = c >> 6, d = c & 63;
#pragma unroll
                for (int i = 0; i < 4; i++) {
                    int m0 = bm * 128 + wm * 64 + i * 16 + lq * 4;
                    int b = m0 >> 11, t = m0 & 2047;
                    half4_t pk;
#pragma unroll
                    for (int r = 0; r < 4; r++) pk[r] = (_Float16)acc[i][j][r];
                    *(half4_t*)&VTh[(((size_t)(b * NH + h)) * HD + d) * TSEQ + t] = pk;
                }
            }
        }
    }
}

// ---------------- flash attention, S^T formulation, 128 q / block ----------------
// Wave owns 2 groups of 16 queries; K-frags and V-frags shared across groups.
// K/V^T staged via global_load_lds (XOR-8 swizzle), double-buffered, 1 barrier/tile.
// PV uses paired 16x16x32 MFMA (key-permuted, permutation applied to both P and V).
__global__ __launch_bounds__(256, 4) void attn_fwd(const _Float16* __restrict__ Qg,
                                                   const _Float16* __restrict__ Kg,
                                                   const _Float16* __restrict__ VTg,
                                                   _Float16* __restrict__ Y) {
    __shared__ __align__(16) _Float16 Ks[2][4096];   // [64 keys][64 d], swizzled
    __shared__ __align__(16) _Float16 Vt[2][4096];   // [64 d][64 keys], swizzled

    const int tid = threadIdx.x;
    const int w = tid >> 6, lane = tid & 63;
    const int l16 = lane & 15, quad = lane >> 4;
    const int bh = blockIdx.y;
    const int xq = blockIdx.x;
    const int qt = ((bh >> 4) & 1) ? (15 - xq) : xq;   // per-CU load balance
    const int b = bh >> 4, h = bh & 15;

    const _Float16* Qb = Qg + (size_t)bh * TSEQ * HD;
    const _Float16* Kb = Kg + (size_t)bh * TSEQ * HD;
    const _Float16* Vb = VTg + (size_t)bh * HD * TSEQ;

    half8 qf[2][2];
#pragma unroll
    for (int g = 0; g < 2; g++) {
        const _Float16* qrow = Qb + (size_t)(qt * 128 + g * 64 + w * 16 + l16) * HD;
        qf[g][0] = *(const half8*)(qrow + quad * 8);
        qf[g][1] = *(const half8*)(qrow + 32 + quad * 8);
    }

    const floatx4 zero = {0.f, 0.f, 0.f, 0.f};
    floatx4 o[2][4];
#pragma unroll
    for (int g = 0; g < 2; g++)
#pragma unroll
        for (int dt = 0; dt < 4; dt++) o[g][dt] = zero;
    float m_run[2] = {-1e30f, -1e30f};
    float l_run[2] = {0.f, 0.f};

    const float kscale = 0.125f * 1.44269504089f;   // 1/sqrt(64) * log2(e)
    const int srow8 = lane >> 3;
    const int scol8 = ((lane & 7) ^ (lane >> 3)) * 8;   // XOR-8 swizzled col (halves)

    auto stage = [&](int bf, int kt2) {
#pragma unroll
        for (int cc = 0; cc < 2; cc++) {
            const int c = w * 2 + cc;
            const int row = c * 8 + srow8;
            async16(Kb + (size_t)(kt2 * 64 + row) * HD + scol8, &Ks[bf][c * 512]);
            async16(Vb + (size_t)row * TSEQ + kt2 * 64 + scol8, &Vt[bf][c * 512]);
        }
    };

    const int kmax = 2 * qt + 1;
    stage(0, 0);
    int buf = 0;
    for (int kt = 0; kt <= kmax; ++kt) {
        __syncthreads();                       // buf staged (vmcnt drain), buf^1 free
        if (kt < kmax) stage(buf ^ 1, kt + 1);

        // K fragments (shared by both q-groups)
        half8 kf0[4], kf1[4];
#pragma unroll
        for (int nj = 0; nj < 4; nj++) {
            const int rb = (nj * 16 + l16) * 64;
            kf0[nj] = *(const half8*)&Ks[buf][rb + ((quad ^ (l16 & 7)) * 8)];
            kf1[nj] = *(const half8*)&Ks[buf][rb + (((quad ^ 4) ^ (l16 & 7)) * 8)];
        }

        const bool doA = (kt <= 2 * qt);
        half8 pf[2][2];
#pragma unroll
        for (int g = 0; g < 2; g++) {
            if (g == 0 && !doA) continue;      // wave-uniform skip (last tile is B-only)
            floatx4 st[4];
#pragma unroll
            for (int nj = 0; nj < 4; nj++) {
                floatx4 t = mfma16x32(kf0[nj], qf[g][0], zero);
                st[nj] = mfma16x32(kf1[nj], qf[g][1], t);
            }
            const int qmine = qt * 128 + g * 64 + w * 16 + l16;
            if (kt * 64 + 63 > qt * 128 + g * 64 + w * 16) {   // wave-uniform mask check
                const int klim = qmine - kt * 64;
#pragma unroll
                for (int nj = 0; nj < 4; nj++)
#pragma unroll
                    for (int r = 0; r < 4; r++) {
                        int key = nj * 16 + quad * 4 + r;
                        if (key > klim) st[nj][r] = -1e30f;
                    }
            }
            float mx = -1e30f;
#pragma unroll
            for (int nj = 0; nj < 4; nj++)
#pragma unroll
                for (int r = 0; r < 4; r++) mx = fmaxf(mx, st[nj][r]);
            mx = fmaxf(mx, __shfl_xor(mx, 16));
            mx = fmaxf(mx, __shfl_xor(mx, 32));
            float mnew = fmaxf(m_run[g], mx);
            float alpha = __builtin_amdgcn_exp2f((m_run[g] - mnew) * kscale);
            m_run[g] = mnew;
            const float coef = -mnew * kscale;
            float rsum = 0.f;
#pragma unroll
            for (int nj = 0; nj < 4; nj++)
#pragma unroll
                for (int r = 0; r < 4; r++) {
                    float p = __builtin_amdgcn_exp2f(fmaf(st[nj][r], kscale, coef));
                    rsum += p;
                    pf[g][nj >> 1][(nj & 1) * 4 + r] = (_Float16)p;
                }
            rsum += __shfl_xor(rsum, 16);
            rsum += __shfl_xor(rsum, 32);
            l_run[g] = l_run[g] * alpha + rsum;
            float ao[4];
#pragma unroll
            for (int r = 0; r < 4; r++) ao[r] = __shfl(alpha, quad * 4 + r);
#pragma unroll
            for (int dt = 0; dt < 4; dt++)
#pragma unroll
                for (int r = 0; r < 4; r++) o[g][dt][r] *= ao[r];
        }

        // O += P*V, paired 16x16x32; V-fragments shared across groups
#pragma unroll
        for (int u = 0; u < 2; u++) {
#pragma unroll
            for (int dt = 0; dt < 4; dt++) {
                const int rb = (dt * 16 + l16) * 64;
                const int g0 = u * 4 + (quad >> 1);
                const int sub = (quad & 1) * 4;
                half4_t lo = *(const half4_t*)&Vt[buf][rb + ((g0 ^ (l16 & 7)) * 8 + sub)];
                half4_t hi = *(const half4_t*)&Vt[buf][rb + (((g0 + 2) ^ (l16 & 7)) * 8 + sub)];
                half8 vf;
                vf[0] = lo[0]; vf[1] = lo[1]; vf[2] = lo[2]; vf[3] = lo[3];
                vf[4] = hi[0]; vf[5] = hi[1]; vf[6] = hi[2]; vf[7] = hi[3];
                if (doA) o[0][dt] = mfma16x32(pf[0][u], vf, o[0][dt]);
                o[1][dt] = mfma16x32(pf[1][u], vf, o[1][dt]);
            }
        }
        buf ^= 1;
    }

#pragma unroll
    for (int g = 0; g < 2; g++) {
        float linv[4];
#pragma unroll
        for (int r = 0; r < 4; r++) linv[r] = 1.0f / __shfl(l_run[g], quad * 4 + r);
#pragma unroll
        for (int dt = 0; dt < 4; dt++)
#pragma unroll
            for (int r = 0; r < 4; r++) {
                int q = qt * 128 + g * 64 + w * 16 + quad * 4 + r;
                int d = dt * 16 + l16;
                Y[((size_t)(b * TSEQ + q)) * CEMB + h * HD + d] = (_Float16)(o[g][dt][r] * linv[r]);
            }
    }
}

extern "C" void kernel_launch(void* const* d_in, const int* in_sizes, int n_in,
                              void* d_out, int out_size, void* d_ws, size_t ws_size,
                              hipStream_t stream) {
    const float* x0     = (const float*)d_in[0];
    const float* w_attn = (const float*)d_in[1];
    const float* w_proj = (const float*)d_in[2];
    float* out = (float*)d_out;

    _Float16* xh  = (_Float16*)d_ws;                       // [8192][1024]
    _Float16* wqt = xh  + (size_t)MROWS * CEMB;            // [3072][1024] (w_attn^T)
    _Float16* wpt = wqt + (size_t)3 * CEMB * CEMB;         // [1024][1024] (w_proj^T)
    _Float16* qh  = wpt + (size_t)CEMB * CEMB;             // Q [bh][t][d]
    _Float16* kh  = qh  + (size_t)MROWS * CEMB;            // K [bh][t][d]
    _Float16* vt  = kh  + (size_t)MROWS * CEMB;            // V^T [bh][d][t]
    _Float16* yh  = vt  + (size_t)MROWS * CEMB;            // [8192][1024]

    cvt_fp32_fp16<<<(MROWS * CEMB) / (256 * 8), 256, 0, stream>>>(x0, xh);
    transpose_cvt<<<dim3(3 * CEMB / 32, CEMB / 32), dim3(32, 8), 0, stream>>>(w_attn, wqt, CEMB, 3 * CEMB);
    transpose_cvt<<<dim3(CEMB / 32, CEMB / 32), dim3(32, 8), 0, stream>>>(w_proj, wpt, CEMB, CEMB);

    gemm_nt<0><<<dim3(MROWS / 128, 3 * CEMB / 128), 256, 0, stream>>>(xh, wqt, nullptr, qh, vt, 3 * CEMB, CEMB);
    attn_fwd<<<dim3(TSEQ / 128, NB * NH), 256, 0, stream>>>(qh, kh, vt, yh);
    gemm_nt<1><<<dim3(MROWS / 128, CEMB / 128), 256, 0, stream>>>(yh, wpt, out, nullptr, nullptr, CEMB, CEMB);
}

// Round 4
// 254.760 us; speedup vs baseline: 1.7411x; 1.0746x over previous
//
#include <hip/hip_runtime.h>

#define TSEQ 2048
#define NB 4
#define NH 16
#define HD 64
#define CEMB 1024
#define MROWS (NB*TSEQ)   // 8192

typedef _Float16 half8 __attribute__((ext_vector_type(8)));
typedef _Float16 half4_t __attribute__((ext_vector_type(4)));
typedef float floatx4 __attribute__((ext_vector_type(4)));

__device__ __forceinline__ floatx4 mfma16x32(half8 a, half8 b, floatx4 c) {
    return __builtin_amdgcn_mfma_f32_16x16x32_f16(a, b, c, 0, 0, 0);
}

__device__ __forceinline__ void async16(const _Float16* g, _Float16* l) {
    __builtin_amdgcn_global_load_lds((const __attribute__((address_space(1))) void*)g,
                                     (__attribute__((address_space(3))) void*)l, 16, 0, 0);
}

// ---------------- fp32 -> fp16 convert (8 elem/thread) ----------------
__global__ __launch_bounds__(256) void cvt_fp32_fp16(const float* __restrict__ in,
                                                     _Float16* __restrict__ out) {
    size_t i = ((size_t)blockIdx.x * 256 + threadIdx.x) * 8;
    float4 a = *(const float4*)(in + i);
    float4 b = *(const float4*)(in + i + 4);
    half8 h;
    h[0] = (_Float16)a.x; h[1] = (_Float16)a.y; h[2] = (_Float16)a.z; h[3] = (_Float16)a.w;
    h[4] = (_Float16)b.x; h[5] = (_Float16)b.y; h[6] = (_Float16)b.z; h[7] = (_Float16)b.w;
    *(half8*)(out + i) = h;
}

// ------------- transpose + convert: in fp32 [R][Ccols] -> out fp16 [Ccols][R] -------------
__global__ __launch_bounds__(256) void transpose_cvt(const float* __restrict__ in,
                                                     _Float16* __restrict__ out,
                                                     int R, int Ccols) {
    __shared__ float tile[32][33];
    int bx = blockIdx.x;
    int by = blockIdx.y;
    int tx = threadIdx.x, ty = threadIdx.y;
    int x = bx * 32 + tx;
#pragma unroll
    for (int i = 0; i < 32; i += 8) {
        int y = by * 32 + ty + i;
        tile[ty + i][tx] = in[(size_t)y * Ccols + x];
    }
    __syncthreads();
#pragma unroll
    for (int i = 0; i < 32; i += 8) {
        int oc = bx * 32 + ty + i;
        int orow = by * 32 + tx;
        out[(size_t)oc * R + orow] = (_Float16)tile[tx][ty + i];
    }
}

// ---------------- NT GEMM: C[m][n] = sum_k A[m][k] * Bt[n][k] ----------------
// m97-style staging + GROUP_M=8 L2 swizzle (round-robin dispatch pins each XCD
// to one bm row per group -> A row tile stays in its 4MiB L2 across all bn).
template<int MODE>
__global__ __launch_bounds__(256, 4) void gemm_nt(const _Float16* __restrict__ A,
                                                  const _Float16* __restrict__ Bt,
                                                  float* __restrict__ Cf,
                                                  _Float16* __restrict__ Ch,
                                                  _Float16* __restrict__ VTh,
                                                  int N, int K) {
    __shared__ __align__(16) _Float16 As[2][4096];   // [128][32] halves, XOR-4 swizzled
    __shared__ __align__(16) _Float16 Bs[2][4096];

    const int tid = threadIdx.x;
    const int wave = tid >> 6, lane = tid & 63;
    const int wm = wave >> 1, wn = wave & 1;
    const int l16 = lane & 15, lq = lane >> 4;

    // L2 group swizzle
    const int pid = blockIdx.x + gridDim.x * blockIdx.y;
    const int nn = gridDim.y;
    const int pig = 8 * nn;
    const int gid = pid / pig;
    const int rem = pid - gid * pig;
    const int bm = gid * 8 + (rem & 7);
    const int bn = rem >> 3;

    const int srow = lane >> 2;                                // within-chunk row
    const int scol = ((lane & 3) ^ ((lane >> 2) & 3)) * 8;     // swizzled col (halves)
    const _Float16* Abase = A + (size_t)(bm * 128) * K;
    const _Float16* Bbase = Bt + (size_t)(bn * 128) * K;

    const floatx4 zero = {0.f, 0.f, 0.f, 0.f};
    floatx4 acc[4][4];
#pragma unroll
    for (int i = 0; i < 4; i++)
#pragma unroll
        for (int j = 0; j < 4; j++) acc[i][j] = zero;

    auto stage = [&](int bf, int k0) {
#pragma unroll
        for (int cc = 0; cc < 2; cc++) {
            const int c = wave * 2 + cc;
            const size_t gofs = (size_t)(c * 16 + srow) * K + k0 + scol;
            async16(Abase + gofs, &As[bf][c * 512]);
            async16(Bbase + gofs, &Bs[bf][c * 512]);
        }
    };

    stage(0, 0);
    int buf = 0;
    for (int k0 = 0; k0 < K; k0 += 32) {
        __syncthreads();                 // implicit vmcnt(0): buf staged, buf^1 free
        if (k0 + 32 < K) stage(buf ^ 1, k0 + 32);
        half8 af[4], bf[4];
#pragma unroll
        for (int i = 0; i < 4; i++) {
            const int sw = (lq ^ (l16 & 3)) * 8;
            af[i] = *(const half8*)&As[buf][(wm * 64 + i * 16 + l16) * 32 + sw];
            bf[i] = *(const half8*)&Bs[buf][(wn * 64 + i * 16 + l16) * 32 + sw];
        }
#pragma unroll
        for (int i = 0; i < 4; i++)
#pragma unroll
            for (int j = 0; j < 4; j++)
                acc[i][j] = mfma16x32(af[i], bf[j], acc[i][j]);
        buf ^= 1;
    }

    if (MODE == 1) {
#pragma unroll
        for (int i = 0; i < 4; i++) {
            int row = bm * 128 + wm * 64 + i * 16 + lq * 4;
#pragma unroll
            for (int j = 0; j < 4; j++) {
                int col = bn * 128 + wn * 64 + j * 16 + l16;
#pragma unroll
                for (int r = 0; r < 4; r++)
                    Cf[(size_t)(row + r) * N + col] = acc[i][j][r];
            }
        }
    } else {
        const int which = bn >> 3;   // block-uniform (128 | 1024)
        if (which < 2) {
#pragma unroll
            for (int j = 0; j < 4; j++) {
                int n = bn * 128 + wn * 64 + j * 16 + l16;
                int c = n & 1023, h = c >> 6, d = c & 63;
                _Float16* dst = Ch + (size_t)which * ((size_t)MROWS * CEMB)
                                   + (size_t)h * (TSEQ * HD) + d;
#pragma unroll
                for (int i = 0; i < 4; i++) {
                    int row = bm * 128 + wm * 64 + i * 16 + lq * 4;
#pragma unroll
                    for (int r = 0; r < 4; r++) {
                        int m = row + r;
                        int b = m >> 11, t = m & 2047;
                        dst[(size_t)b * (NH * TSEQ * HD) + (size_t)t * HD] = (_Float16)acc[i][j][r];
                    }
                }
            }
        } else {
            // V^T: [bh][d][t], 4 consecutive t -> packed b64 store
#pragma unroll
            for (int j = 0; j < 4; j++) {
                int n = bn * 128 + wn * 64 + j * 16 + l16;
                int c = n & 1023, h = c >> 6, d = c & 63;
#pragma unroll
                for (int i = 0; i < 4; i++) {
                    int m0 = bm * 128 + wm * 64 + i * 16 + lq * 4;
                    int b = m0 >> 11, t = m0 & 2047;
                    half4_t pk;
#pragma unroll
                    for (int r = 0; r < 4; r++) pk[r] = (_Float16)acc[i][j][r];
                    *(half4_t*)&VTh[(((size_t)(b * NH + h)) * HD + d) * TSEQ + t] = pk;
                }
            }
        }
    }
}

// ---------------- flash attention, S^T formulation, max-free softmax ----------------
// Q pre-scaled by (1/sqrt(d))*log2(e) -> S comes out in log2 domain.
// p = exp2(S) directly: |S|<=~10 so p<=2^10 << fp16 max, l<=2048*2^10 fits fp32.
// Softmax normalization is scale-invariant -> identical result, but ZERO
// cross-lane ops per tile, no running max, no O rescale. l reduced at epilogue.
__global__ __launch_bounds__(256, 4) void attn_fwd(const _Float16* __restrict__ Qg,
                                                   const _Float16* __restrict__ Kg,
                                                   const _Float16* __restrict__ VTg,
                                                   _Float16* __restrict__ Y) {
    __shared__ __align__(16) _Float16 Ks[2][4096];   // [64 keys][64 d], swizzled
    __shared__ __align__(16) _Float16 Vt[2][4096];   // [64 d][64 keys], swizzled

    const int tid = threadIdx.x;
    const int w = tid >> 6, lane = tid & 63;
    const int l16 = lane & 15, quad = lane >> 4;
    const int bh = blockIdx.y;
    const int xq = blockIdx.x;
    const int qt = ((bh >> 4) & 1) ? (15 - xq) : xq;   // per-CU load balance
    const int b = bh >> 4, h = bh & 15;

    const _Float16* Qb = Qg + (size_t)bh * TSEQ * HD;
    const _Float16* Kb = Kg + (size_t)bh * TSEQ * HD;
    const _Float16* Vb = VTg + (size_t)bh * HD * TSEQ;

    const _Float16 ksc = (_Float16)(0.125f * 1.44269504089f);  // 1/sqrt(64)*log2(e)
    half8 qf[2][2];
#pragma unroll
    for (int g = 0; g < 2; g++) {
        const _Float16* qrow = Qb + (size_t)(qt * 128 + g * 64 + w * 16 + l16) * HD;
        qf[g][0] = *(const half8*)(qrow + quad * 8);
        qf[g][1] = *(const half8*)(qrow + 32 + quad * 8);
#pragma unroll
        for (int e = 0; e < 8; e++) { qf[g][0][e] *= ksc; qf[g][1][e] *= ksc; }
    }

    const floatx4 zero = {0.f, 0.f, 0.f, 0.f};
    floatx4 o[2][4];
#pragma unroll
    for (int g = 0; g < 2; g++)
#pragma unroll
        for (int dt = 0; dt < 4; dt++) o[g][dt] = zero;
    float lsum[2] = {0.f, 0.f};

    const int srow8 = lane >> 3;
    const int scol8 = ((lane & 7) ^ (lane >> 3)) * 8;   // XOR-8 swizzled col (halves)

    auto stage = [&](int bf, int kt2) {
#pragma unroll
        for (int cc = 0; cc < 2; cc++) {
            const int c = w * 2 + cc;
            const int row = c * 8 + srow8;
            async16(Kb + (size_t)(kt2 * 64 + row) * HD + scol8, &Ks[bf][c * 512]);
            async16(Vb + (size_t)row * TSEQ + kt2 * 64 + scol8, &Vt[bf][c * 512]);
        }
    };

    const int kmax = 2 * qt + 1;
    stage(0, 0);
    int buf = 0;
    for (int kt = 0; kt <= kmax; ++kt) {
        __syncthreads();                       // buf staged (vmcnt drain), buf^1 free
        if (kt < kmax) stage(buf ^ 1, kt + 1);

        // K fragments (shared by both q-groups)
        half8 kf0[4], kf1[4];
#pragma unroll
        for (int nj = 0; nj < 4; nj++) {
            const int rb = (nj * 16 + l16) * 64;
            kf0[nj] = *(const half8*)&Ks[buf][rb + ((quad ^ (l16 & 7)) * 8)];
            kf1[nj] = *(const half8*)&Ks[buf][rb + (((quad ^ 4) ^ (l16 & 7)) * 8)];
        }

        const bool doA = (kt <= 2 * qt);
        half8 pf[2][2];
#pragma unroll
        for (int g = 0; g < 2; g++) {
            if (g == 0 && !doA) continue;      // wave-uniform skip (last tile is g=1 only)
            floatx4 st[4];
#pragma unroll
            for (int nj = 0; nj < 4; nj++) {
                floatx4 t = mfma16x32(kf0[nj], qf[g][0], zero);
                st[nj] = mfma16x32(kf1[nj], qf[g][1], t);
            }
            if (kt * 64 + 63 > qt * 128 + g * 64 + w * 16) {   // boundary tiles only
                const int klim = qt * 128 + g * 64 + w * 16 + l16 - kt * 64;
#pragma unroll
                for (int nj = 0; nj < 4; nj++)
#pragma unroll
                    for (int r = 0; r < 4; r++) {
                        int key = nj * 16 + quad * 4 + r;
                        if (key > klim) st[nj][r] = -1e30f;   // exp2 -> 0
                    }
            }
#pragma unroll
            for (int nj = 0; nj < 4; nj++)
#pragma unroll
                for (int r = 0; r < 4; r++) {
                    float p = __builtin_amdgcn_exp2f(st[nj][r]);
                    lsum[g] += p;
                    pf[g][nj >> 1][(nj & 1) * 4 + r] = (_Float16)p;
                }
        }

        // O += P*V, paired 16x16x32; V-fragments shared across groups
#pragma unroll
        for (int u = 0; u < 2; u++) {
#pragma unroll
            for (int dt = 0; dt < 4; dt++) {
                const int rb = (dt * 16 + l16) * 64;
                const int g0 = u * 4 + (quad >> 1);
                const int sub = (quad & 1) * 4;
                half4_t lo = *(const half4_t*)&Vt[buf][rb + ((g0 ^ (l16 & 7)) * 8 + sub)];
                half4_t hi = *(const half4_t*)&Vt[buf][rb + (((g0 + 2) ^ (l16 & 7)) * 8 + sub)];
                half8 vf;
                vf[0] = lo[0]; vf[1] = lo[1]; vf[2] = lo[2]; vf[3] = lo[3];
                vf[4] = hi[0]; vf[5] = hi[1]; vf[6] = hi[2]; vf[7] = hi[3];
                if (doA) o[0][dt] = mfma16x32(pf[0][u], vf, o[0][dt]);
                o[1][dt] = mfma16x32(pf[1][u], vf, o[1][dt]);
            }
        }
        buf ^= 1;
    }

#pragma unroll
    for (int g = 0; g < 2; g++) {
        float lt = lsum[g];
        lt += __shfl_xor(lt, 16);
        lt += __shfl_xor(lt, 32);          // lt = full l for query w*16+l16 (this group)
        float linv[4];
#pragma unroll
        for (int r = 0; r < 4; r++) linv[r] = 1.0f / __shfl(lt, quad * 4 + r);
#pragma unroll
        for (int dt = 0; dt < 4; dt++)
#pragma unroll
            for (int r = 0; r < 4; r++) {
                int q = qt * 128 + g * 64 + w * 16 + quad * 4 + r;
                int d = dt * 16 + l16;
                Y[((size_t)(b * TSEQ + q)) * CEMB + h * HD + d] = (_Float16)(o[g][dt][r] * linv[r]);
            }
    }
}

extern "C" void kernel_launch(void* const* d_in, const int* in_sizes, int n_in,
                              void* d_out, int out_size, void* d_ws, size_t ws_size,
                              hipStream_t stream) {
    const float* x0     = (const float*)d_in[0];
    const float* w_attn = (const float*)d_in[1];
    const float* w_proj = (const float*)d_in[2];
    float* out = (float*)d_out;

    _Float16* xh  = (_Float16*)d_ws;                       // [8192][1024]
    _Float16* wqt = xh  + (size_t)MROWS * CEMB;            // [3072][1024] (w_attn^T)
    _Float16* wpt = wqt + (size_t)3 * CEMB * CEMB;         // [1024][1024] (w_proj^T)
    _Float16* qh  = wpt + (size_t)CEMB * CEMB;             // Q [bh][t][d]
    _Float16* kh  = qh  + (size_t)MROWS * CEMB;            // K [bh][t][d]
    _Float16* vt  = kh  + (size_t)MROWS * CEMB;            // V^T [bh][d][t]
    _Float16* yh  = vt  + (size_t)MROWS * CEMB;            // [8192][1024]

    cvt_fp32_fp16<<<(MROWS * CEMB) / (256 * 8), 256, 0, stream>>>(x0, xh);
    transpose_cvt<<<dim3(3 * CEMB / 32, CEMB / 32), dim3(32, 8), 0, stream>>>(w_attn, wqt, CEMB, 3 * CEMB);
    transpose_cvt<<<dim3(CEMB / 32, CEMB / 32), dim3(32, 8), 0, stream>>>(w_proj, wpt, CEMB, CEMB);

    gemm_nt<0><<<dim3(MROWS / 128, 3 * CEMB / 128), 256, 0, stream>>>(xh, wqt, nullptr, qh, vt, 3 * CEMB, CEMB);
    attn_fwd<<<dim3(TSEQ / 128, NB * NH), 256, 0, stream>>>(qh, kh, vt, yh);
    gemm_nt<1><<<dim3(MROWS / 128, CEMB / 128), 256, 0, stream>>>(yh, wpt, out, nullptr, nullptr, CEMB, CEMB);
}

// Round 5
// 251.948 us; speedup vs baseline: 1.7605x; 1.0112x over previous
//
#include <hip/hip_runtime.h>

#define TSEQ 2048
#define NB 4
#define NH 16
#define HD 64
#define CEMB 1024
#define MROWS (NB*TSEQ)   // 8192

typedef _Float16 half8 __attribute__((ext_vector_type(8)));
typedef _Float16 half4_t __attribute__((ext_vector_type(4)));
typedef float floatx4 __attribute__((ext_vector_type(4)));

__device__ __forceinline__ floatx4 mfma16x32(half8 a, half8 b, floatx4 c) {
    return __builtin_amdgcn_mfma_f32_16x16x32_f16(a, b, c, 0, 0, 0);
}

__device__ __forceinline__ void async16(const _Float16* g, _Float16* l) {
    __builtin_amdgcn_global_load_lds((const __attribute__((address_space(1))) void*)g,
                                     (__attribute__((address_space(3))) void*)l, 16, 0, 0);
}

// ---------------- fp32 -> fp16 convert (8 elem/thread) ----------------
__global__ __launch_bounds__(256) void cvt_fp32_fp16(const float* __restrict__ in,
                                                     _Float16* __restrict__ out) {
    size_t i = ((size_t)blockIdx.x * 256 + threadIdx.x) * 8;
    float4 a = *(const float4*)(in + i);
    float4 b = *(const float4*)(in + i + 4);
    half8 h;
    h[0] = (_Float16)a.x; h[1] = (_Float16)a.y; h[2] = (_Float16)a.z; h[3] = (_Float16)a.w;
    h[4] = (_Float16)b.x; h[5] = (_Float16)b.y; h[6] = (_Float16)b.z; h[7] = (_Float16)b.w;
    *(half8*)(out + i) = h;
}

// ------------- transpose + convert: in fp32 [R][Ccols] -> out fp16 [Ccols][R] -------------
__global__ __launch_bounds__(256) void transpose_cvt(const float* __restrict__ in,
                                                     _Float16* __restrict__ out,
                                                     int R, int Ccols) {
    __shared__ float tile[32][33];
    int bx = blockIdx.x;
    int by = blockIdx.y;
    int tx = threadIdx.x, ty = threadIdx.y;
    int x = bx * 32 + tx;
#pragma unroll
    for (int i = 0; i < 32; i += 8) {
        int y = by * 32 + ty + i;
        tile[ty + i][tx] = in[(size_t)y * Ccols + x];
    }
    __syncthreads();
#pragma unroll
    for (int i = 0; i < 32; i += 8) {
        int oc = bx * 32 + ty + i;
        int orow = by * 32 + tx;
        out[(size_t)oc * R + orow] = (_Float16)tile[tx][ty + i];
    }
}

// ---------------- NT GEMM: C[m][n] = sum_k A[m][k] * Bt[n][k] ----------------
// m97-style staging + GROUP_M=8 L2 swizzle. LDS XOR swizzle keyed on (row>>1)&3
// (bank-alias period of a 64B row is 2 rows) -> 2-way max on ds_read_b128 = free.
template<int MODE>
__global__ __launch_bounds__(256, 4) void gemm_nt(const _Float16* __restrict__ A,
                                                  const _Float16* __restrict__ Bt,
                                                  float* __restrict__ Cf,
                                                  _Float16* __restrict__ Ch,
                                                  _Float16* __restrict__ VTh,
                                                  int N, int K) {
    __shared__ __align__(16) _Float16 As[2][4096];   // [128][32] halves, XOR swizzled
    __shared__ __align__(16) _Float16 Bs[2][4096];

    const int tid = threadIdx.x;
    const int wave = tid >> 6, lane = tid & 63;
    const int wm = wave >> 1, wn = wave & 1;
    const int l16 = lane & 15, lq = lane >> 4;

    // L2 group swizzle
    const int pid = blockIdx.x + gridDim.x * blockIdx.y;
    const int nn = gridDim.y;
    const int pig = 8 * nn;
    const int gid = pid / pig;
    const int rem = pid - gid * pig;
    const int bm = gid * 8 + (rem & 7);
    const int bn = rem >> 3;

    const int srow = lane >> 2;                                 // within-chunk row
    const int scol = ((lane & 3) ^ ((lane >> 3) & 3)) * 8;      // swizzled col (halves)
    const _Float16* Abase = A + (size_t)(bm * 128) * K;
    const _Float16* Bbase = Bt + (size_t)(bn * 128) * K;

    const floatx4 zero = {0.f, 0.f, 0.f, 0.f};
    floatx4 acc[4][4];
#pragma unroll
    for (int i = 0; i < 4; i++)
#pragma unroll
        for (int j = 0; j < 4; j++) acc[i][j] = zero;

    auto stage = [&](int bf, int k0) {
#pragma unroll
        for (int cc = 0; cc < 2; cc++) {
            const int c = wave * 2 + cc;
            const size_t gofs = (size_t)(c * 16 + srow) * K + k0 + scol;
            async16(Abase + gofs, &As[bf][c * 512]);
            async16(Bbase + gofs, &Bs[bf][c * 512]);
        }
    };

    stage(0, 0);
    int buf = 0;
    const int sw = (lq ^ ((l16 >> 1) & 3)) * 8;   // read-side swizzle (halves)
    for (int k0 = 0; k0 < K; k0 += 32) {
        __syncthreads();                 // implicit vmcnt(0): buf staged, buf^1 free
        if (k0 + 32 < K) stage(buf ^ 1, k0 + 32);
        half8 af[4], bf[4];
#pragma unroll
        for (int i = 0; i < 4; i++) {
            af[i] = *(const half8*)&As[buf][(wm * 64 + i * 16 + l16) * 32 + sw];
            bf[i] = *(const half8*)&Bs[buf][(wn * 64 + i * 16 + l16) * 32 + sw];
        }
#pragma unroll
        for (int i = 0; i < 4; i++)
#pragma unroll
            for (int j = 0; j < 4; j++)
                acc[i][j] = mfma16x32(af[i], bf[j], acc[i][j]);
        buf ^= 1;
    }

    if (MODE == 1) {
#pragma unroll
        for (int i = 0; i < 4; i++) {
            int row = bm * 128 + wm * 64 + i * 16 + lq * 4;
#pragma unroll
            for (int j = 0; j < 4; j++) {
                int col = bn * 128 + wn * 64 + j * 16 + l16;
#pragma unroll
                for (int r = 0; r < 4; r++)
                    Cf[(size_t)(row + r) * N + col] = acc[i][j][r];
            }
        }
    } else {
        const int which = bn >> 3;   // block-uniform (128 | 1024)
        if (which < 2) {
#pragma unroll
            for (int j = 0; j < 4; j++) {
                int n = bn * 128 + wn * 64 + j * 16 + l16;
                int c = n & 1023, h = c >> 6, d = c & 63;
                _Float16* dst = Ch + (size_t)which * ((size_t)MROWS * CEMB)
                                   + (size_t)h * (TSEQ * HD) + d;
#pragma unroll
                for (int i = 0; i < 4; i++) {
                    int row = bm * 128 + wm * 64 + i * 16 + lq * 4;
#pragma unroll
                    for (int r = 0; r < 4; r++) {
                        int m = row + r;
                        int b = m >> 11, t = m & 2047;
                        dst[(size_t)b * (NH * TSEQ * HD) + (size_t)t * HD] = (_Float16)acc[i][j][r];
                    }
                }
            }
        } else {
            // V^T: [bh][d][t], 4 consecutive t -> packed b64 store
#pragma unroll
            for (int j = 0; j < 4; j++) {
                int n = bn * 128 + wn * 64 + j * 16 + l16;
                int c = n & 1023, h = c >> 6, d = c & 63;
#pragma unroll
                for (int i = 0; i < 4; i++) {
                    int m0 = bm * 128 + wm * 64 + i * 16 + lq * 4;
                    int b = m0 >> 11, t = m0 & 2047;
                    half4_t pk;
#pragma unroll
                    for (int r = 0; r < 4; r++) pk[r] = (_Float16)acc[i][j][r];
                    *(half4_t*)&VTh[(((size_t)(b * NH + h)) * HD + d) * TSEQ + t] = pk;
                }
            }
        }
    }
}

// ---------------- flash attention, S^T formulation, max-free softmax ----------------
// Each block serially processes qt-pair (xq, 15-xq): constant 34 tile-units per
// block -> zero makespan imbalance (512 identical blocks, 2/CU).
__global__ __launch_bounds__(256, 4) void attn_fwd(const _Float16* __restrict__ Qg,
                                                   const _Float16* __restrict__ Kg,
                                                   const _Float16* __restrict__ VTg,
                                                   _Float16* __restrict__ Y) {
    __shared__ __align__(16) _Float16 Ks[2][4096];   // [64 keys][64 d], swizzled
    __shared__ __align__(16) _Float16 Vt[2][4096];   // [64 d][64 keys], swizzled

    const int tid = threadIdx.x;
    const int w = tid >> 6, lane = tid & 63;
    const int l16 = lane & 15, quad = lane >> 4;
    const int bh = blockIdx.y;
    const int xq = blockIdx.x;   // 0..7
    const int b = bh >> 4, h = bh & 15;

    const _Float16* Qb = Qg + (size_t)bh * TSEQ * HD;
    const _Float16* Kb = Kg + (size_t)bh * TSEQ * HD;
    const _Float16* Vb = VTg + (size_t)bh * HD * TSEQ;

    const _Float16 ksc = (_Float16)(0.125f * 1.44269504089f);  // 1/sqrt(64)*log2(e)
    const floatx4 zero = {0.f, 0.f, 0.f, 0.f};

    const int srow8 = lane >> 3;
    const int scol8 = ((lane & 7) ^ (lane >> 3)) * 8;   // XOR-8 swizzled col (halves)

    auto stage = [&](int bf, int kt2) {
#pragma unroll
        for (int cc = 0; cc < 2; cc++) {
            const int c = w * 2 + cc;
            const int row = c * 8 + srow8;
            async16(Kb + (size_t)(kt2 * 64 + row) * HD + scol8, &Ks[bf][c * 512]);
            async16(Vb + (size_t)row * TSEQ + kt2 * 64 + scol8, &Vt[bf][c * 512]);
        }
    };

    for (int ph = 0; ph < 2; ph++) {
        const int qt = ph ? (15 - xq) : xq;

        half8 qf[2][2];
#pragma unroll
        for (int g = 0; g < 2; g++) {
            const _Float16* qrow = Qb + (size_t)(qt * 128 + g * 64 + w * 16 + l16) * HD;
            qf[g][0] = *(const half8*)(qrow + quad * 8);
            qf[g][1] = *(const half8*)(qrow + 32 + quad * 8);
#pragma unroll
            for (int e = 0; e < 8; e++) { qf[g][0][e] *= ksc; qf[g][1][e] *= ksc; }
        }

        floatx4 o[2][4];
#pragma unroll
        for (int g = 0; g < 2; g++)
#pragma unroll
            for (int dt = 0; dt < 4; dt++) o[g][dt] = zero;
        float lsum[2] = {0.f, 0.f};

        if (ph) __syncthreads();     // all waves done reading prev phase's LDS
        stage(0, 0);
        int buf = 0;
        const int kmax = 2 * qt + 1;
        for (int kt = 0; kt <= kmax; ++kt) {
            __syncthreads();                   // buf staged (vmcnt drain), buf^1 free
            if (kt < kmax) stage(buf ^ 1, kt + 1);

            // K fragments (shared by both q-groups)
            half8 kf0[4], kf1[4];
#pragma unroll
            for (int nj = 0; nj < 4; nj++) {
                const int rb = (nj * 16 + l16) * 64;
                kf0[nj] = *(const half8*)&Ks[buf][rb + ((quad ^ (l16 & 7)) * 8)];
                kf1[nj] = *(const half8*)&Ks[buf][rb + (((quad ^ 4) ^ (l16 & 7)) * 8)];
            }

            const bool doA = (kt <= 2 * qt);
            half8 pf[2][2];
#pragma unroll
            for (int g = 0; g < 2; g++) {
                if (g == 0 && !doA) continue;  // wave-uniform skip (last tile is g=1 only)
                floatx4 st[4];
#pragma unroll
                for (int nj = 0; nj < 4; nj++) {
                    floatx4 t = mfma16x32(kf0[nj], qf[g][0], zero);
                    st[nj] = mfma16x32(kf1[nj], qf[g][1], t);
                }
                if (kt * 64 + 63 > qt * 128 + g * 64 + w * 16) {   // boundary tiles only
                    const int klim = qt * 128 + g * 64 + w * 16 + l16 - kt * 64;
#pragma unroll
                    for (int nj = 0; nj < 4; nj++)
#pragma unroll
                        for (int r = 0; r < 4; r++) {
                            int key = nj * 16 + quad * 4 + r;
                            if (key > klim) st[nj][r] = -1e30f;   // exp2 -> 0
                        }
                }
#pragma unroll
                for (int nj = 0; nj < 4; nj++)
#pragma unroll
                    for (int r = 0; r < 4; r++) {
                        float p = __builtin_amdgcn_exp2f(st[nj][r]);
                        lsum[g] += p;
                        pf[g][nj >> 1][(nj & 1) * 4 + r] = (_Float16)p;
                    }
            }

            // O += P*V, paired 16x16x32; V-fragments shared across groups
#pragma unroll
            for (int u = 0; u < 2; u++) {
#pragma unroll
                for (int dt = 0; dt < 4; dt++) {
                    const int rb = (dt * 16 + l16) * 64;
                    const int g0 = u * 4 + (quad >> 1);
                    const int sub = (quad & 1) * 4;
                    half4_t lo = *(const half4_t*)&Vt[buf][rb + ((g0 ^ (l16 & 7)) * 8 + sub)];
                    half4_t hi = *(const half4_t*)&Vt[buf][rb + (((g0 + 2) ^ (l16 & 7)) * 8 + sub)];
                    half8 vf;
                    vf[0] = lo[0]; vf[1] = lo[1]; vf[2] = lo[2]; vf[3] = lo[3];
                    vf[4] = hi[0]; vf[5] = hi[1]; vf[6] = hi[2]; vf[7] = hi[3];
                    if (doA) o[0][dt] = mfma16x32(pf[0][u], vf, o[0][dt]);
                    o[1][dt] = mfma16x32(pf[1][u], vf, o[1][dt]);
                }
            }
            buf ^= 1;
        }

#pragma unroll
        for (int g = 0; g < 2; g++) {
            float lt = lsum[g];
            lt += __shfl_xor(lt, 16);
            lt += __shfl_xor(lt, 32);      // lt = full l for query w*16+l16 (this group)
            float linv[4];
#pragma unroll
            for (int r = 0; r < 4; r++) linv[r] = 1.0f / __shfl(lt, quad * 4 + r);
#pragma unroll
            for (int dt = 0; dt < 4; dt++)
#pragma unroll
                for (int r = 0; r < 4; r++) {
                    int q = qt * 128 + g * 64 + w * 16 + quad * 4 + r;
                    int d = dt * 16 + l16;
                    Y[((size_t)(b * TSEQ + q)) * CEMB + h * HD + d] = (_Float16)(o[g][dt][r] * linv[r]);
                }
        }
    }
}

extern "C" void kernel_launch(void* const* d_in, const int* in_sizes, int n_in,
                              void* d_out, int out_size, void* d_ws, size_t ws_size,
                              hipStream_t stream) {
    const float* x0     = (const float*)d_in[0];
    const float* w_attn = (const float*)d_in[1];
    const float* w_proj = (const float*)d_in[2];
    float* out = (float*)d_out;

    _Float16* xh  = (_Float16*)d_ws;                       // [8192][1024]
    _Float16* wqt = xh  + (size_t)MROWS * CEMB;            // [3072][1024] (w_attn^T)
    _Float16* wpt = wqt + (size_t)3 * CEMB * CEMB;         // [1024][1024] (w_proj^T)
    _Float16* qh  = wpt + (size_t)CEMB * CEMB;             // Q [bh][t][d]
    _Float16* kh  = qh  + (size_t)MROWS * CEMB;            // K [bh][t][d]
    _Float16* vt  = kh  + (size_t)MROWS * CEMB;            // V^T [bh][d][t]
    _Float16* yh  = vt  + (size_t)MROWS * CEMB;            // [8192][1024]

    cvt_fp32_fp16<<<(MROWS * CEMB) / (256 * 8), 256, 0, stream>>>(x0, xh);
    transpose_cvt<<<dim3(3 * CEMB / 32, CEMB / 32), dim3(32, 8), 0, stream>>>(w_attn, wqt, CEMB, 3 * CEMB);
    transpose_cvt<<<dim3(CEMB / 32, CEMB / 32), dim3(32, 8), 0, stream>>>(w_proj, wpt, CEMB, CEMB);

    gemm_nt<0><<<dim3(MROWS / 128, 3 * CEMB / 128), 256, 0, stream>>>(xh, wqt, nullptr, qh, vt, 3 * CEMB, CEMB);
    attn_fwd<<<dim3(TSEQ / 256, NB * NH), 256, 0, stream>>>(qh, kh, vt, yh);
    gemm_nt<1><<<dim3(MROWS / 128, CEMB / 128), 256, 0, stream>>>(yh, wpt, out, nullptr, nullptr, CEMB, CEMB);
}